// Round 7
// baseline (209.870 us; speedup 1.0000x reference)
//
#include <hip/hip_runtime.h>
#include <cstdint>

__device__ __forceinline__ float leaky(float v) { return v >= 0.f ? v : 0.01f * v; }

// ================= Encoder level 0: staged conv5x5 + leaky + pool ====================
// Weights read directly from global (wave-uniform -> s_load), no LDS staging.
__global__ void __launch_bounds__(256) enc0_k(
    const float* __restrict__ x1, const float* __restrict__ x2,
    const float* __restrict__ w, const float* __restrict__ bias,
    float* __restrict__ c2, float* __restrict__ pout)
{
    constexpr int R = 256;
    __shared__ float ss[3 * 36 * 36];
    int t = threadIdx.x;
    int n = blockIdx.y;
    int tileY = blockIdx.x >> 3, tileX = blockIdx.x & 7;
    int Y0 = 32 * tileY, X0 = 32 * tileX;
    const float* src = (n < 2) ? x1 + (size_t)n * 3 * R * R
                               : x2 + (size_t)(n - 2) * 3 * R * R;

    for (int ci = 0; ci < 3; ++ci) {
        const float* sp = src + (size_t)ci * R * R;
        for (int i = t; i < 1296; i += 256) {
            int r = i / 36, col = i - r * 36;
            int gy = Y0 - 2 + r, gx = X0 - 2 + col;
            float v = 0.f;
            if (gy >= 0 && gy < R && gx >= 0 && gx < R) v = sp[gy * R + gx];
            ss[ci * 1296 + i] = v;
        }
    }
    __syncthreads();

    int qx = t & 15, qy = t >> 4;
    float acc[4][2][2];
#pragma unroll
    for (int co = 0; co < 4; ++co) {
        float b0 = bias[co];
        acc[co][0][0] = b0; acc[co][0][1] = b0; acc[co][1][0] = b0; acc[co][1][1] = b0;
    }
#pragma unroll
    for (int ci = 0; ci < 3; ++ci) {
        const float* sp = &ss[ci * 1296 + (2 * qy) * 36 + 2 * qx];
        float S[6][6];
#pragma unroll
        for (int i = 0; i < 6; ++i)
#pragma unroll
            for (int j = 0; j < 6; ++j) S[i][j] = sp[i * 36 + j];
#pragma unroll
        for (int co = 0; co < 4; ++co) {
#pragma unroll
            for (int dy = 0; dy < 5; ++dy) {
#pragma unroll
                for (int dx = 0; dx < 5; ++dx) {
                    float wv = w[(co * 3 + ci) * 25 + dy * 5 + dx];
                    acc[co][0][0] = fmaf(wv, S[dy][dx],         acc[co][0][0]);
                    acc[co][0][1] = fmaf(wv, S[dy][dx + 1],     acc[co][0][1]);
                    acc[co][1][0] = fmaf(wv, S[dy + 1][dx],     acc[co][1][0]);
                    acc[co][1][1] = fmaf(wv, S[dy + 1][dx + 1], acc[co][1][1]);
                }
            }
        }
    }
#pragma unroll
    for (int co = 0; co < 4; ++co) {
        float v00 = leaky(acc[co][0][0]), v01 = leaky(acc[co][0][1]);
        float v10 = leaky(acc[co][1][0]), v11 = leaky(acc[co][1][1]);
        if (n >= 2) {
            float* op = c2 + ((size_t)((n - 2) * 4 + co)) * R * R + (Y0 + 2 * qy) * R + X0 + 2 * qx;
            float2 a; a.x = v00; a.y = v01; *(float2*)op = a;
            float2 b2; b2.x = v10; b2.y = v11; *(float2*)(op + R) = b2;
        }
        float pv = fmaxf(fmaxf(v00, v01), fmaxf(v10, v11));
        pout[((size_t)(n * 4 + co)) * 16384 + (16 * tileY + qy) * 128 + 16 * tileX + qx] = pv;
    }
}

// ================= Encoder: conv5x5 pad2 + leaky + fused 2x2 maxpool (levels 1-3) ====
template<int R, int CI, int CO, int COG>
__global__ void __launch_bounds__(256) enc_k(
    const float* __restrict__ src1, const float* __restrict__ src2,
    const float* __restrict__ w, const float* __restrict__ bias,
    float* __restrict__ c2, float* __restrict__ pout)
{
    constexpr int W = R, H = R, Wt = R / 2;
    constexpr int RPB = 256 / Wt;
    __shared__ float pl[(RPB / 2) * COG * Wt];

    int t = threadIdx.x;
    int gid = blockIdx.x * 256 + t;
    int col = gid % Wt;
    int y = (gid / Wt) % H;
    int n = (gid / (Wt * H)) & 3;
    int g = gid / (Wt * H * 4);
    const float* wg = w + g * COG * CI * 25;

    const float* sp = (n < 2) ? (src1 + (size_t)n * CI * H * W)
                              : (src2 + (size_t)(n - 2) * CI * H * W);
    int x0 = col * 2;

    float acc[COG][2];
#pragma unroll
    for (int cg = 0; cg < COG; ++cg) { float b0 = bias[g * COG + cg]; acc[cg][0] = b0; acc[cg][1] = b0; }

    bool okr[5], okc[3];
#pragma unroll
    for (int i = 0; i < 5; ++i) { int yy = y + i - 2; okr[i] = (yy >= 0) && (yy < H); }
#pragma unroll
    for (int j = 0; j < 3; ++j) { int xx = x0 + 2 * j - 2; okc[j] = (xx >= 0) && (xx < W); }

    for (int ci = 0; ci < CI; ++ci) {
        const float* s = sp + ci * H * W + (y - 2) * W + (x0 - 2);
        float p[5][6];
#pragma unroll
        for (int i = 0; i < 5; ++i) {
#pragma unroll
            for (int j = 0; j < 3; ++j) {
                if (okr[i] & okc[j]) {
                    float2 v = *(const float2*)(s + i * W + 2 * j);
                    p[i][2 * j] = v.x; p[i][2 * j + 1] = v.y;
                } else { p[i][2 * j] = 0.f; p[i][2 * j + 1] = 0.f; }
            }
        }
#pragma unroll
        for (int cg = 0; cg < COG; ++cg) {
#pragma unroll
            for (int dy = 0; dy < 5; ++dy) {
#pragma unroll
                for (int dx = 0; dx < 5; ++dx) {
                    float wv = wg[(cg * CI + ci) * 25 + dy * 5 + dx];
                    acc[cg][0] = fmaf(wv, p[dy][dx],     acc[cg][0]);
                    acc[cg][1] = fmaf(wv, p[dy][dx + 1], acc[cg][1]);
                }
            }
        }
    }

    int r = t / Wt;
    float m[COG];
#pragma unroll
    for (int cg = 0; cg < COG; ++cg) {
        float v0 = leaky(acc[cg][0]), v1 = leaky(acc[cg][1]);
        m[cg] = fmaxf(v0, v1);
        if (n >= 2) {
            float2 stv; stv.x = v0; stv.y = v1;
            *(float2*)(c2 + ((size_t)((n - 2) * CO + g * COG + cg)) * H * W + y * W + x0) = stv;
        }
    }
    if (r & 1) {
#pragma unroll
        for (int cg = 0; cg < COG; ++cg)
            pl[((r >> 1) * COG + cg) * Wt + col] = m[cg];
    }
    __syncthreads();
    if (!(r & 1)) {
#pragma unroll
        for (int cg = 0; cg < COG; ++cg) {
            float pv = fmaxf(m[cg], pl[((r >> 1) * COG + cg) * Wt + col]);
            pout[((size_t)(n * CO + g * COG + cg)) * Wt * Wt + (y >> 1) * Wt + col] = pv;
        }
    }
}

// ================= Attention: all 4 levels in ONE launch =============================
template<int C, int RP, int SHIFT>
__device__ __forceinline__ void attn_body(
    const float* __restrict__ pool, const int* __restrict__ pts,
    float* __restrict__ out, int tile, int b)
{
    constexpr int P = RP * RP;
    __shared__ float qs[32 * C];
    int t = threadIdx.x;
    if (t < 32) {
        int l = t;
        int py = pts[(b * 32 + l) * 2 + 0] >> SHIFT;
        int px = pts[(b * 32 + l) * 2 + 1] >> SHIFT;
        const float* qp = pool + (size_t)(b * C) * P + py * RP + px;
        float v[C]; float s = 0.f;
#pragma unroll
        for (int c = 0; c < C; ++c) { v[c] = qp[c * P]; s += v[c] * v[c]; }
        float invn = 1.f / fmaxf(sqrtf(s), 1e-8f);
#pragma unroll
        for (int c = 0; c < C; ++c) qs[l * C + c] = v[c] * invn;
    }
    __syncthreads();
    int p = tile * 256 + t;
    const float* hp = pool + (size_t)((2 + b) * C) * P + p;
    float v[C]; float s = 0.f;
#pragma unroll
    for (int c = 0; c < C; ++c) { v[c] = hp[c * P]; s += v[c] * v[c]; }
    float invn2 = 1.f / fmaxf(sqrtf(s), 1e-8f);
#pragma unroll 4
    for (int l = 0; l < 32; ++l) {
        float d = 0.f;
#pragma unroll
        for (int c = 0; c < C; ++c) d = fmaf(v[c], qs[l * C + c], d);
        out[(size_t)(b * 32 + l) * P + p] = d * invn2;
    }
}

__global__ void __launch_bounds__(256) attn_all_k(
    const float* __restrict__ p0, const float* __restrict__ p1,
    const float* __restrict__ p2, const float* __restrict__ p3,
    const int* __restrict__ pts,
    float* __restrict__ at0, float* __restrict__ at1,
    float* __restrict__ at2, float* __restrict__ at3)
{
    int bx = blockIdx.x;
    if (bx < 128)      attn_body<4, 128, 1>(p0, pts, at0, bx >> 1, bx & 1);
    else if (bx < 160) { int r = bx - 128; attn_body<8, 64, 2>(p1, pts, at1, r >> 1, r & 1); }
    else if (bx < 168) { int r = bx - 160; attn_body<16, 32, 3>(p2, pts, at2, r >> 1, r & 1); }
    else               { int r = bx - 168; attn_body<16, 16, 4>(p3, pts, at3, r >> 1, r & 1); }
}

// ================= dec0: conv3x3 fused upsample+concat, 2x2 tile (unstaged) ==========
template<int R, int CP, int CF, int CO, int COG, bool TILEDPREV, bool DOLEAKY>
__global__ void __launch_bounds__(256) dec_k(
    const float* __restrict__ prev, const float* __restrict__ attn,
    const float* __restrict__ feat, const float* __restrict__ w,
    const float* __restrict__ bias, float* __restrict__ out)
{
    constexpr int CIN = CP + 1 + CF, Rh = R / 2;
    int t = threadIdx.x, gid = blockIdx.x * 256 + t;
    int tx = gid % Rh;
    int ty = (gid / Rh) % Rh;
    int k = (gid / (Rh * Rh)) & 63;
    int g = gid / (Rh * Rh * 64);
    const float* wg = w + g * COG * CIN * 9;

    float acc[COG][2][2];
#pragma unroll
    for (int cg = 0; cg < COG; ++cg) {
        float b0 = bias[g * COG + cg];
        acc[cg][0][0] = b0; acc[cg][0][1] = b0; acc[cg][1][0] = b0; acc[cg][1][1] = b0;
    }

    bool hr[3], hc[3], fr[4], fc[4];
#pragma unroll
    for (int i = 0; i < 3; ++i) {
        int yy = ty - 1 + i; hr[i] = (yy >= 0) && (yy < Rh);
        int xx = tx - 1 + i; hc[i] = (xx >= 0) && (xx < Rh);
    }
#pragma unroll
    for (int i = 0; i < 4; ++i) {
        int yy = 2 * ty - 1 + i; fr[i] = (yy >= 0) && (yy < R);
        int xx = 2 * tx - 1 + i; fc[i] = (xx >= 0) && (xx < R);
    }

    constexpr int HM0[3] = {0, 1, 1};
    constexpr int HM1[3] = {1, 1, 2};

    int np = TILEDPREV ? (2 + (k & 1)) : k;
    int kf = k & 1;

    for (int ci = 0; ci < CP + 1; ++ci) {
        const float* bp = (ci < CP) ? (prev + ((size_t)(np * CP + ci)) * Rh * Rh)
                                    : (attn + (size_t)k * Rh * Rh);
        bp += (ty - 1) * Rh + (tx - 1);
        float P[3][3];
#pragma unroll
        for (int i = 0; i < 3; ++i)
#pragma unroll
            for (int j = 0; j < 3; ++j)
                P[i][j] = (hr[i] & hc[j]) ? bp[i * Rh + j] : 0.f;
#pragma unroll
        for (int cg = 0; cg < COG; ++cg) {
#pragma unroll
            for (int dy = 0; dy < 3; ++dy) {
#pragma unroll
                for (int dx = 0; dx < 3; ++dx) {
                    float wv = wg[(cg * CIN + ci) * 9 + dy * 3 + dx];
                    acc[cg][0][0] = fmaf(wv, P[HM0[dy]][HM0[dx]], acc[cg][0][0]);
                    acc[cg][0][1] = fmaf(wv, P[HM0[dy]][HM1[dx]], acc[cg][0][1]);
                    acc[cg][1][0] = fmaf(wv, P[HM1[dy]][HM0[dx]], acc[cg][1][0]);
                    acc[cg][1][1] = fmaf(wv, P[HM1[dy]][HM1[dx]], acc[cg][1][1]);
                }
            }
        }
    }

    for (int cf = 0; cf < CF; ++cf) {
        const float* bp = feat + ((size_t)(kf * CF + cf)) * R * R + (2 * ty - 1) * R + (2 * tx - 1);
        float F[4][4];
#pragma unroll
        for (int i = 0; i < 4; ++i)
#pragma unroll
            for (int j = 0; j < 4; ++j)
                F[i][j] = (fr[i] & fc[j]) ? bp[i * R + j] : 0.f;
#pragma unroll
        for (int cg = 0; cg < COG; ++cg) {
#pragma unroll
            for (int dy = 0; dy < 3; ++dy) {
#pragma unroll
                for (int dx = 0; dx < 3; ++dx) {
                    float wv = wg[(cg * CIN + CP + 1 + cf) * 9 + dy * 3 + dx];
                    acc[cg][0][0] = fmaf(wv, F[dy][dx],         acc[cg][0][0]);
                    acc[cg][0][1] = fmaf(wv, F[dy][dx + 1],     acc[cg][0][1]);
                    acc[cg][1][0] = fmaf(wv, F[dy + 1][dx],     acc[cg][1][0]);
                    acc[cg][1][1] = fmaf(wv, F[dy + 1][dx + 1], acc[cg][1][1]);
                }
            }
        }
    }

#pragma unroll
    for (int cg = 0; cg < COG; ++cg) {
        float v00 = acc[cg][0][0], v01 = acc[cg][0][1];
        float v10 = acc[cg][1][0], v11 = acc[cg][1][1];
        if (DOLEAKY) { v00 = leaky(v00); v01 = leaky(v01); v10 = leaky(v10); v11 = leaky(v11); }
        float* op = out + ((size_t)(k * CO + g * COG + cg)) * R * R + (2 * ty) * R + 2 * tx;
        float2 a; a.x = v00; a.y = v01; *(float2*)op = a;
        float2 b2; b2.x = v10; b2.y = v11; *(float2*)(op + R) = b2;
    }
}

// ================= dec2/dec3: 4-k same-parity block, LDS staged, 2x2 quads ===========
// Weights scalar from global; activations LDS; feat e/o column split (stride-1 reads).
template<int R, int CP, int CF, int CO, int MINW, bool DOLEAKY>
__global__ void __launch_bounds__(256, MINW) deckq_k(
    const float* __restrict__ prev, const float* __restrict__ attn,
    const float* __restrict__ feat, const float* __restrict__ w,
    const float* __restrict__ bias, float* __restrict__ out)
{
    constexpr int CIN = CP + 1 + CF, Rh = R / 2, TX = R / 16;
    __shared__ float sf[CF * 324];          // [cf][18 rows][Fe 9 | Fo 9]
    __shared__ float sh[4][(CP + 1) * 100];

    int t = threadIdx.x;
    int kg = blockIdx.y;
    int p = kg & 1;
    int kbase = (kg >> 1) * 8 + p;          // k = kbase + 2*j, j=0..3
    int tileY = blockIdx.x / TX, tileX = blockIdx.x % TX;
    int Y0 = 16 * tileY, X0 = 16 * tileX;
    int hy0 = 8 * tileY - 1, hx0 = 8 * tileX - 1;

    for (int i = t; i < CF * 324; i += 256) {
        int c = i / 324, rem = i - c * 324;
        int r = rem / 18, wc = rem - r * 18;
        int gy = Y0 - 1 + r, gx = X0 - 1 + wc;
        float v = 0.f;
        if (gy >= 0 && gy < R && gx >= 0 && gx < R)
            v = feat[((size_t)(p * CF + c)) * R * R + gy * R + gx];
        sf[c * 324 + r * 18 + (wc & 1) * 9 + (wc >> 1)] = v;
    }
    for (int i = t; i < CP * 100; i += 256) {
        int c = i / 100, rem = i - c * 100;
        int r = rem / 10, col = rem - r * 10;
        int gy = hy0 + r, gx = hx0 + col;
        bool ok = (gy >= 0) && (gy < Rh) && (gx >= 0) && (gx < Rh);
        int off = gy * Rh + gx;
#pragma unroll
        for (int j = 0; j < 4; ++j) {
            float v = 0.f;
            if (ok) v = prev[((size_t)((kbase + 2 * j) * CP + c)) * Rh * Rh + off];
            sh[j][i] = v;
        }
    }
    if (t < 100) {
        int r = t / 10, col = t - r * 10;
        int gy = hy0 + r, gx = hx0 + col;
        bool ok = (gy >= 0) && (gy < Rh) && (gx >= 0) && (gx < Rh);
        int off = gy * Rh + gx;
#pragma unroll
        for (int j = 0; j < 4; ++j) {
            float v = 0.f;
            if (ok) v = attn[(size_t)(kbase + 2 * j) * Rh * Rh + off];
            sh[j][CP * 100 + t] = v;
        }
    }
    __syncthreads();

    int ksub = t >> 6, q = t & 63, qx = q & 7, qy = q >> 3;
    int k = kbase + 2 * ksub;

    float acc[CO][2][2];
#pragma unroll
    for (int co = 0; co < CO; ++co) {
        float b0 = bias[co];
        acc[co][0][0] = b0; acc[co][0][1] = b0; acc[co][1][0] = b0; acc[co][1][1] = b0;
    }

#pragma unroll
    for (int ci = 0; ci < CP + 1; ++ci) {
        const float* hp = &sh[ksub][ci * 100 + qy * 10 + qx];
        float P[3][3];
#pragma unroll
        for (int i = 0; i < 3; ++i)
#pragma unroll
            for (int j = 0; j < 3; ++j) P[i][j] = hp[i * 10 + j];
#pragma unroll
        for (int co = 0; co < CO; ++co) {
#pragma unroll
            for (int dy = 0; dy < 3; ++dy) {
#pragma unroll
                for (int dx = 0; dx < 3; ++dx) {
                    float wv = w[(co * CIN + ci) * 9 + dy * 3 + dx];
                    acc[co][0][0] = fmaf(wv, P[(0 + dy + 1) >> 1][(0 + dx + 1) >> 1], acc[co][0][0]);
                    acc[co][0][1] = fmaf(wv, P[(0 + dy + 1) >> 1][(1 + dx + 1) >> 1], acc[co][0][1]);
                    acc[co][1][0] = fmaf(wv, P[(1 + dy + 1) >> 1][(0 + dx + 1) >> 1], acc[co][1][0]);
                    acc[co][1][1] = fmaf(wv, P[(1 + dy + 1) >> 1][(1 + dx + 1) >> 1], acc[co][1][1]);
                }
            }
        }
    }
#pragma unroll
    for (int cf = 0; cf < CF; ++cf) {
        const float* fb = &sf[cf * 324];
        float F[4][4];
#pragma unroll
        for (int i = 0; i < 4; ++i) {
            int wr = (2 * qy + i) * 18;
            F[i][0] = fb[wr + qx];
            F[i][1] = fb[wr + 9 + qx];
            F[i][2] = fb[wr + qx + 1];
            F[i][3] = fb[wr + 9 + qx + 1];
        }
#pragma unroll
        for (int co = 0; co < CO; ++co) {
#pragma unroll
            for (int dy = 0; dy < 3; ++dy) {
#pragma unroll
                for (int dx = 0; dx < 3; ++dx) {
                    float wv = w[(co * CIN + CP + 1 + cf) * 9 + dy * 3 + dx];
                    acc[co][0][0] = fmaf(wv, F[0 + dy][0 + dx], acc[co][0][0]);
                    acc[co][0][1] = fmaf(wv, F[0 + dy][1 + dx], acc[co][0][1]);
                    acc[co][1][0] = fmaf(wv, F[1 + dy][0 + dx], acc[co][1][0]);
                    acc[co][1][1] = fmaf(wv, F[1 + dy][1 + dx], acc[co][1][1]);
                }
            }
        }
    }

#pragma unroll
    for (int co = 0; co < CO; ++co) {
        float v00 = acc[co][0][0], v01 = acc[co][0][1];
        float v10 = acc[co][1][0], v11 = acc[co][1][1];
        if (DOLEAKY) { v00 = leaky(v00); v01 = leaky(v01); v10 = leaky(v10); v11 = leaky(v11); }
        float* op = out + ((size_t)(k * CO + co)) * R * R + (Y0 + 2 * qy) * R + X0 + 2 * qx;
        float2 a; a.x = v00; a.y = v01; *(float2*)op = a;
        float2 b2; b2.x = v10; b2.y = v11; *(float2*)(op + R) = b2;
    }
}

// ================= dec1: 2-k same-parity block, ALL CO=8, staged, 2x1 px/thread ======
// Weights scalar from global; LDS only for activations (34 KB -> 4 blocks/CU).
__global__ void __launch_bounds__(256, 2) dec1b_k(
    const float* __restrict__ prev, const float* __restrict__ attn,
    const float* __restrict__ feat, const float* __restrict__ w,
    const float* __restrict__ bias, float* __restrict__ out)
{
    constexpr int R = 64, CP = 16, CF = 16, CIN = 33, Rh = 32, CO = 8;
    __shared__ float sf[CF * 324];          // [cf][18 rows][Fe 9 | Fo 9]
    __shared__ float sh[2][(CP + 1) * 100]; // [ksub][ci][10][10]

    int t = threadIdx.x;
    int kg = blockIdx.y;                // 0..31
    int p = kg & 1;
    int kbase = (kg >> 1) * 4 + p;      // k = kbase + 2*j, j=0..1
    int tileY = blockIdx.x >> 2, tileX = blockIdx.x & 3;
    int Y0 = 16 * tileY, X0 = 16 * tileX;
    int hy0 = 8 * tileY - 1, hx0 = 8 * tileX - 1;

    for (int i = t; i < CF * 324; i += 256) {
        int c = i / 324, rem = i - c * 324;
        int r = rem / 18, wc = rem - r * 18;
        int gy = Y0 - 1 + r, gx = X0 - 1 + wc;
        float v = 0.f;
        if (gy >= 0 && gy < R && gx >= 0 && gx < R)
            v = feat[((size_t)(p * CF + c)) * R * R + gy * R + gx];
        sf[c * 324 + r * 18 + (wc & 1) * 9 + (wc >> 1)] = v;
    }
    for (int i = t; i < CP * 100; i += 256) {
        int c = i / 100, rem = i - c * 100;
        int r = rem / 10, col = rem - r * 10;
        int gy = hy0 + r, gx = hx0 + col;
        bool ok = (gy >= 0) && (gy < Rh) && (gx >= 0) && (gx < Rh);
        int off = gy * Rh + gx;
#pragma unroll
        for (int j = 0; j < 2; ++j) {
            float v = 0.f;
            if (ok) v = prev[((size_t)((kbase + 2 * j) * CP + c)) * Rh * Rh + off];
            sh[j][i] = v;
        }
    }
    if (t < 100) {
        int r = t / 10, col = t - r * 10;
        int gy = hy0 + r, gx = hx0 + col;
        bool ok = (gy >= 0) && (gy < Rh) && (gx >= 0) && (gx < Rh);
        int off = gy * Rh + gx;
#pragma unroll
        for (int j = 0; j < 2; ++j) {
            float v = 0.f;
            if (ok) v = attn[(size_t)(kbase + 2 * j) * Rh * Rh + off];
            sh[j][CP * 100 + t] = v;
        }
    }
    __syncthreads();

    int ksub = t >> 7, r2 = t & 127, py = r2 >> 3, px = r2 & 7;
    int k = kbase + 2 * ksub;

    float acc[CO][2];
#pragma unroll
    for (int co = 0; co < CO; ++co) {
        float b0 = bias[co];
        acc[co][0] = b0; acc[co][1] = b0;
    }

    int rr0 = (py + 1) >> 1;
    int rr1 = (py + 2) >> 1;
    int rr2 = (py + 3) >> 1;

#pragma unroll
    for (int ci = 0; ci < CP + 1; ++ci) {
        const float* hp = &sh[ksub][ci * 100 + px];
        float P[3][3];
#pragma unroll
        for (int j = 0; j < 3; ++j) {
            P[0][j] = hp[rr0 * 10 + j];
            P[1][j] = hp[rr1 * 10 + j];
            P[2][j] = hp[rr2 * 10 + j];
        }
#pragma unroll
        for (int co = 0; co < CO; ++co) {
#pragma unroll
            for (int dy = 0; dy < 3; ++dy) {
#pragma unroll
                for (int dx = 0; dx < 3; ++dx) {
                    float wv = w[(co * CIN + ci) * 9 + dy * 3 + dx];
                    acc[co][0] = fmaf(wv, P[dy][(dx + 1) >> 1], acc[co][0]);
                    acc[co][1] = fmaf(wv, P[dy][(dx + 2) >> 1], acc[co][1]);
                }
            }
        }
    }
#pragma unroll
    for (int cf = 0; cf < CF; ++cf) {
        const float* fb = &sf[cf * 324 + py * 18 + px];
        float Fe[3][2], Fo[3][2];
#pragma unroll
        for (int i = 0; i < 3; ++i) {
            Fe[i][0] = fb[i * 18];
            Fe[i][1] = fb[i * 18 + 1];
            Fo[i][0] = fb[i * 18 + 9];
            Fo[i][1] = fb[i * 18 + 10];
        }
#pragma unroll
        for (int co = 0; co < CO; ++co) {
#pragma unroll
            for (int dy = 0; dy < 3; ++dy) {
                const float* wp = &w[(co * CIN + CP + 1 + cf) * 9 + dy * 3];
                acc[co][0] = fmaf(wp[0], Fe[dy][0], acc[co][0]);
                acc[co][0] = fmaf(wp[1], Fo[dy][0], acc[co][0]);
                acc[co][0] = fmaf(wp[2], Fe[dy][1], acc[co][0]);
                acc[co][1] = fmaf(wp[0], Fo[dy][0], acc[co][1]);
                acc[co][1] = fmaf(wp[1], Fe[dy][1], acc[co][1]);
                acc[co][1] = fmaf(wp[2], Fo[dy][1], acc[co][1]);
            }
        }
    }

#pragma unroll
    for (int co = 0; co < CO; ++co) {
        float v0 = leaky(acc[co][0]), v1 = leaky(acc[co][1]);
        float* op = out + ((size_t)(k * CO + co)) * R * R + (Y0 + py) * R + X0 + 2 * px;
        float2 a; a.x = v0; a.y = v1; *(float2*)op = a;
    }
}

extern "C" void kernel_launch(void* const* d_in, const int* in_sizes, int n_in,
                              void* d_out, int out_size, void* d_ws, size_t ws_size,
                              hipStream_t stream)
{
    (void)in_sizes; (void)n_in; (void)out_size; (void)ws_size;
    const float* x1 = (const float*)d_in[0];
    const float* x2 = (const float*)d_in[1];
    const int* pts = (const int*)d_in[2];
    const float* ew[4] = {(const float*)d_in[3], (const float*)d_in[5],
                          (const float*)d_in[7], (const float*)d_in[9]};
    const float* eb[4] = {(const float*)d_in[4], (const float*)d_in[6],
                          (const float*)d_in[8], (const float*)d_in[10]};
    const float* dw[4] = {(const float*)d_in[11], (const float*)d_in[13],
                          (const float*)d_in[15], (const float*)d_in[17]};
    const float* db[4] = {(const float*)d_in[12], (const float*)d_in[14],
                          (const float*)d_in[16], (const float*)d_in[18]};

    float* wsp = (float*)d_ws;
    size_t off = 0;
    auto A = [&](size_t n) { float* p = wsp + off; off += n; return p; };

    float* p0 = A((size_t)4 * 4 * 128 * 128);
    float* p1 = A((size_t)4 * 8 * 64 * 64);
    float* p2 = A((size_t)4 * 16 * 32 * 32);
    float* p3 = A((size_t)4 * 16 * 16 * 16);
    float* c2_0 = A((size_t)2 * 4 * 256 * 256);
    float* c2_1 = A((size_t)2 * 8 * 128 * 128);
    float* c2_2 = A((size_t)2 * 16 * 64 * 64);
    float* c2_3 = A((size_t)2 * 16 * 32 * 32);
    float* at0 = A((size_t)64 * 128 * 128);
    float* at1 = A((size_t)64 * 64 * 64);
    float* at2 = A((size_t)64 * 32 * 32);
    float* at3 = A((size_t)64 * 16 * 16);
    float* dec0 = A((size_t)64 * 16 * 32 * 32);
    float* dec1 = A((size_t)64 * 8 * 64 * 64);
    float* dec2 = A((size_t)64 * 4 * 128 * 128);
    float* outp = (float*)d_out;

    // ---- Encoder ----
    { dim3 g(64, 4); enc0_k<<<g, 256, 0, stream>>>(x1, x2, ew[0], eb[0], c2_0, p0); }
    enc_k<128, 4, 8, 2><<<512, 256, 0, stream>>>(p0, p0 + (size_t)2 * 4 * 128 * 128,
                                                 ew[1], eb[1], c2_1, p1);
    enc_k<64, 8, 16, 2><<<256, 256, 0, stream>>>(p1, p1 + (size_t)2 * 8 * 64 * 64,
                                                 ew[2], eb[2], c2_2, p2);
    enc_k<32, 16, 16, 1><<<128, 256, 0, stream>>>(p2, p2 + (size_t)2 * 16 * 32 * 32,
                                                  ew[3], eb[3], c2_3, p3);

    // ---- Attention: single launch for all 4 levels ----
    attn_all_k<<<170, 256, 0, stream>>>(p0, p1, p2, p3, pts, at0, at1, at2, at3);

    // ---- Decoder ----
    dec_k<32, 16, 16, 16, 4, true, true><<<256, 256, 0, stream>>>(p3, at3, c2_3, dw[0], db[0], dec0);
    { dim3 g(16, 32); dec1b_k<<<g, 256, 0, stream>>>(dec0, at2, c2_2, dw[1], db[1], dec1); }
    { dim3 g(64, 16); deckq_k<128, 8, 8, 4, 4, true><<<g, 256, 0, stream>>>(dec1, at1, c2_1, dw[2], db[2], dec2); }
    { dim3 g(256, 16); deckq_k<256, 4, 4, 1, 5, false><<<g, 256, 0, stream>>>(dec2, at0, c2_0, dw[3], db[3], outp); }
}

// Round 8
// 190.023 us; speedup vs baseline: 1.1044x; 1.1044x over previous
//
#include <hip/hip_runtime.h>
#include <cstdint>

__device__ __forceinline__ float leaky(float v) { return v >= 0.f ? v : 0.01f * v; }

// ================= Encoder level 0: staged conv5x5 + leaky + pool ====================
__global__ void __launch_bounds__(256) enc0_k(
    const float* __restrict__ x1, const float* __restrict__ x2,
    const float* __restrict__ w, const float* __restrict__ bias,
    float* __restrict__ c2, float* __restrict__ pout)
{
    constexpr int R = 256;
    __shared__ float ss[3 * 36 * 36];
    __shared__ float ws[4 * 3 * 25 + 4];
    int t = threadIdx.x;
    int n = blockIdx.y;
    int tileY = blockIdx.x >> 3, tileX = blockIdx.x & 7;
    int Y0 = 32 * tileY, X0 = 32 * tileX;
    const float* src = (n < 2) ? x1 + (size_t)n * 3 * R * R
                               : x2 + (size_t)(n - 2) * 3 * R * R;

    for (int i = t; i < 300; i += 256) ws[i] = w[i];
    if (t < 4) ws[300 + t] = bias[t];
    for (int ci = 0; ci < 3; ++ci) {
        const float* sp = src + (size_t)ci * R * R;
        for (int i = t; i < 1296; i += 256) {
            int r = i / 36, col = i - r * 36;
            int gy = Y0 - 2 + r, gx = X0 - 2 + col;
            float v = 0.f;
            if (gy >= 0 && gy < R && gx >= 0 && gx < R) v = sp[gy * R + gx];
            ss[ci * 1296 + i] = v;
        }
    }
    __syncthreads();

    int qx = t & 15, qy = t >> 4;
    float acc[4][2][2];
#pragma unroll
    for (int co = 0; co < 4; ++co) {
        float b0 = ws[300 + co];
        acc[co][0][0] = b0; acc[co][0][1] = b0; acc[co][1][0] = b0; acc[co][1][1] = b0;
    }
#pragma unroll
    for (int ci = 0; ci < 3; ++ci) {
        const float* sp = &ss[ci * 1296 + (2 * qy) * 36 + 2 * qx];
        float S[6][6];
#pragma unroll
        for (int i = 0; i < 6; ++i)
#pragma unroll
            for (int j = 0; j < 6; ++j) S[i][j] = sp[i * 36 + j];
#pragma unroll
        for (int co = 0; co < 4; ++co) {
#pragma unroll
            for (int dy = 0; dy < 5; ++dy) {
#pragma unroll
                for (int dx = 0; dx < 5; ++dx) {
                    float wv = ws[(co * 3 + ci) * 25 + dy * 5 + dx];
                    acc[co][0][0] = fmaf(wv, S[dy][dx],         acc[co][0][0]);
                    acc[co][0][1] = fmaf(wv, S[dy][dx + 1],     acc[co][0][1]);
                    acc[co][1][0] = fmaf(wv, S[dy + 1][dx],     acc[co][1][0]);
                    acc[co][1][1] = fmaf(wv, S[dy + 1][dx + 1], acc[co][1][1]);
                }
            }
        }
    }
#pragma unroll
    for (int co = 0; co < 4; ++co) {
        float v00 = leaky(acc[co][0][0]), v01 = leaky(acc[co][0][1]);
        float v10 = leaky(acc[co][1][0]), v11 = leaky(acc[co][1][1]);
        if (n >= 2) {
            float* op = c2 + ((size_t)((n - 2) * 4 + co)) * R * R + (Y0 + 2 * qy) * R + X0 + 2 * qx;
            float2 a; a.x = v00; a.y = v01; *(float2*)op = a;
            float2 b2; b2.x = v10; b2.y = v11; *(float2*)(op + R) = b2;
        }
        float pv = fmaxf(fmaxf(v00, v01), fmaxf(v10, v11));
        pout[((size_t)(n * 4 + co)) * 16384 + (16 * tileY + qy) * 128 + 16 * tileX + qx] = pv;
    }
}

// ================= Encoder: conv5x5 pad2 + leaky + fused 2x2 maxpool (levels 1-3) ====
template<int R, int CI, int CO, int COG>
__global__ void __launch_bounds__(256) enc_k(
    const float* __restrict__ src1, const float* __restrict__ src2,
    const float* __restrict__ w, const float* __restrict__ bias,
    float* __restrict__ c2, float* __restrict__ pout)
{
    constexpr int W = R, H = R, Wt = R / 2;
    constexpr int RPB = 256 / Wt;
    __shared__ float ws[COG * CI * 25];
    __shared__ float pl[(RPB / 2) * COG * Wt];

    int t = threadIdx.x;
    int gid = blockIdx.x * 256 + t;
    int col = gid % Wt;
    int y = (gid / Wt) % H;
    int n = (gid / (Wt * H)) & 3;
    int g = gid / (Wt * H * 4);

    for (int i = t; i < COG * CI * 25; i += 256) ws[i] = w[g * COG * CI * 25 + i];
    __syncthreads();

    const float* sp = (n < 2) ? (src1 + (size_t)n * CI * H * W)
                              : (src2 + (size_t)(n - 2) * CI * H * W);
    int x0 = col * 2;

    float acc[COG][2];
#pragma unroll
    for (int cg = 0; cg < COG; ++cg) { float b0 = bias[g * COG + cg]; acc[cg][0] = b0; acc[cg][1] = b0; }

    bool okr[5], okc[3];
#pragma unroll
    for (int i = 0; i < 5; ++i) { int yy = y + i - 2; okr[i] = (yy >= 0) && (yy < H); }
#pragma unroll
    for (int j = 0; j < 3; ++j) { int xx = x0 + 2 * j - 2; okc[j] = (xx >= 0) && (xx < W); }

    for (int ci = 0; ci < CI; ++ci) {
        const float* s = sp + ci * H * W + (y - 2) * W + (x0 - 2);
        float p[5][6];
#pragma unroll
        for (int i = 0; i < 5; ++i) {
#pragma unroll
            for (int j = 0; j < 3; ++j) {
                if (okr[i] & okc[j]) {
                    float2 v = *(const float2*)(s + i * W + 2 * j);
                    p[i][2 * j] = v.x; p[i][2 * j + 1] = v.y;
                } else { p[i][2 * j] = 0.f; p[i][2 * j + 1] = 0.f; }
            }
        }
#pragma unroll
        for (int cg = 0; cg < COG; ++cg) {
#pragma unroll
            for (int dy = 0; dy < 5; ++dy) {
#pragma unroll
                for (int dx = 0; dx < 5; ++dx) {
                    float wv = ws[(cg * CI + ci) * 25 + dy * 5 + dx];
                    acc[cg][0] = fmaf(wv, p[dy][dx],     acc[cg][0]);
                    acc[cg][1] = fmaf(wv, p[dy][dx + 1], acc[cg][1]);
                }
            }
        }
    }

    int r = t / Wt;
    float m[COG];
#pragma unroll
    for (int cg = 0; cg < COG; ++cg) {
        float v0 = leaky(acc[cg][0]), v1 = leaky(acc[cg][1]);
        m[cg] = fmaxf(v0, v1);
        if (n >= 2) {
            float2 stv; stv.x = v0; stv.y = v1;
            *(float2*)(c2 + ((size_t)((n - 2) * CO + g * COG + cg)) * H * W + y * W + x0) = stv;
        }
    }
    if (r & 1) {
#pragma unroll
        for (int cg = 0; cg < COG; ++cg)
            pl[((r >> 1) * COG + cg) * Wt + col] = m[cg];
    }
    __syncthreads();
    if (!(r & 1)) {
#pragma unroll
        for (int cg = 0; cg < COG; ++cg) {
            float pv = fmaxf(m[cg], pl[((r >> 1) * COG + cg) * Wt + col]);
            pout[((size_t)(n * CO + g * COG + cg)) * Wt * Wt + (y >> 1) * Wt + col] = pv;
        }
    }
}

// ================= Attention: all 4 levels in ONE launch =============================
template<int C, int RP, int SHIFT>
__device__ __forceinline__ void attn_body(
    const float* __restrict__ pool, const int* __restrict__ pts,
    float* __restrict__ out, int tile, int b)
{
    constexpr int P = RP * RP;
    __shared__ float qs[32 * C];
    int t = threadIdx.x;
    if (t < 32) {
        int l = t;
        int py = pts[(b * 32 + l) * 2 + 0] >> SHIFT;
        int px = pts[(b * 32 + l) * 2 + 1] >> SHIFT;
        const float* qp = pool + (size_t)(b * C) * P + py * RP + px;
        float v[C]; float s = 0.f;
#pragma unroll
        for (int c = 0; c < C; ++c) { v[c] = qp[c * P]; s += v[c] * v[c]; }
        float invn = 1.f / fmaxf(sqrtf(s), 1e-8f);
#pragma unroll
        for (int c = 0; c < C; ++c) qs[l * C + c] = v[c] * invn;
    }
    __syncthreads();
    int p = tile * 256 + t;
    const float* hp = pool + (size_t)((2 + b) * C) * P + p;
    float v[C]; float s = 0.f;
#pragma unroll
    for (int c = 0; c < C; ++c) { v[c] = hp[c * P]; s += v[c] * v[c]; }
    float invn2 = 1.f / fmaxf(sqrtf(s), 1e-8f);
#pragma unroll 4
    for (int l = 0; l < 32; ++l) {
        float d = 0.f;
#pragma unroll
        for (int c = 0; c < C; ++c) d = fmaf(v[c], qs[l * C + c], d);
        out[(size_t)(b * 32 + l) * P + p] = d * invn2;
    }
}

__global__ void __launch_bounds__(256) attn_all_k(
    const float* __restrict__ p0, const float* __restrict__ p1,
    const float* __restrict__ p2, const float* __restrict__ p3,
    const int* __restrict__ pts,
    float* __restrict__ at0, float* __restrict__ at1,
    float* __restrict__ at2, float* __restrict__ at3)
{
    int bx = blockIdx.x;
    if (bx < 128)      attn_body<4, 128, 1>(p0, pts, at0, bx >> 1, bx & 1);
    else if (bx < 160) { int r = bx - 128; attn_body<8, 64, 2>(p1, pts, at1, r >> 1, r & 1); }
    else if (bx < 168) { int r = bx - 160; attn_body<16, 32, 3>(p2, pts, at2, r >> 1, r & 1); }
    else               { int r = bx - 168; attn_body<16, 16, 4>(p3, pts, at3, r >> 1, r & 1); }
}

// ================= dec0: conv3x3 fused upsample+concat, 2x2 tile (unstaged) ==========
template<int R, int CP, int CF, int CO, int COG, bool TILEDPREV, bool DOLEAKY>
__global__ void __launch_bounds__(256) dec_k(
    const float* __restrict__ prev, const float* __restrict__ attn,
    const float* __restrict__ feat, const float* __restrict__ w,
    const float* __restrict__ bias, float* __restrict__ out)
{
    constexpr int CIN = CP + 1 + CF, Rh = R / 2;
    __shared__ float ws[COG * CIN * 9];
    int t = threadIdx.x, gid = blockIdx.x * 256 + t;
    int tx = gid % Rh;
    int ty = (gid / Rh) % Rh;
    int k = (gid / (Rh * Rh)) & 63;
    int g = gid / (Rh * Rh * 64);

    for (int i = t; i < COG * CIN * 9; i += 256) ws[i] = w[g * COG * CIN * 9 + i];
    __syncthreads();

    float acc[COG][2][2];
#pragma unroll
    for (int cg = 0; cg < COG; ++cg) {
        float b0 = bias[g * COG + cg];
        acc[cg][0][0] = b0; acc[cg][0][1] = b0; acc[cg][1][0] = b0; acc[cg][1][1] = b0;
    }

    bool hr[3], hc[3], fr[4], fc[4];
#pragma unroll
    for (int i = 0; i < 3; ++i) {
        int yy = ty - 1 + i; hr[i] = (yy >= 0) && (yy < Rh);
        int xx = tx - 1 + i; hc[i] = (xx >= 0) && (xx < Rh);
    }
#pragma unroll
    for (int i = 0; i < 4; ++i) {
        int yy = 2 * ty - 1 + i; fr[i] = (yy >= 0) && (yy < R);
        int xx = 2 * tx - 1 + i; fc[i] = (xx >= 0) && (xx < R);
    }

    constexpr int HM0[3] = {0, 1, 1};
    constexpr int HM1[3] = {1, 1, 2};

    int np = TILEDPREV ? (2 + (k & 1)) : k;
    int kf = k & 1;

    for (int ci = 0; ci < CP + 1; ++ci) {
        const float* bp = (ci < CP) ? (prev + ((size_t)(np * CP + ci)) * Rh * Rh)
                                    : (attn + (size_t)k * Rh * Rh);
        bp += (ty - 1) * Rh + (tx - 1);
        float P[3][3];
#pragma unroll
        for (int i = 0; i < 3; ++i)
#pragma unroll
            for (int j = 0; j < 3; ++j)
                P[i][j] = (hr[i] & hc[j]) ? bp[i * Rh + j] : 0.f;
#pragma unroll
        for (int cg = 0; cg < COG; ++cg) {
#pragma unroll
            for (int dy = 0; dy < 3; ++dy) {
#pragma unroll
                for (int dx = 0; dx < 3; ++dx) {
                    float wv = ws[(cg * CIN + ci) * 9 + dy * 3 + dx];
                    acc[cg][0][0] = fmaf(wv, P[HM0[dy]][HM0[dx]], acc[cg][0][0]);
                    acc[cg][0][1] = fmaf(wv, P[HM0[dy]][HM1[dx]], acc[cg][0][1]);
                    acc[cg][1][0] = fmaf(wv, P[HM1[dy]][HM0[dx]], acc[cg][1][0]);
                    acc[cg][1][1] = fmaf(wv, P[HM1[dy]][HM1[dx]], acc[cg][1][1]);
                }
            }
        }
    }

    for (int cf = 0; cf < CF; ++cf) {
        const float* bp = feat + ((size_t)(kf * CF + cf)) * R * R + (2 * ty - 1) * R + (2 * tx - 1);
        float F[4][4];
#pragma unroll
        for (int i = 0; i < 4; ++i)
#pragma unroll
            for (int j = 0; j < 4; ++j)
                F[i][j] = (fr[i] & fc[j]) ? bp[i * R + j] : 0.f;
#pragma unroll
        for (int cg = 0; cg < COG; ++cg) {
#pragma unroll
            for (int dy = 0; dy < 3; ++dy) {
#pragma unroll
                for (int dx = 0; dx < 3; ++dx) {
                    float wv = ws[(cg * CIN + CP + 1 + cf) * 9 + dy * 3 + dx];
                    acc[cg][0][0] = fmaf(wv, F[dy][dx],         acc[cg][0][0]);
                    acc[cg][0][1] = fmaf(wv, F[dy][dx + 1],     acc[cg][0][1]);
                    acc[cg][1][0] = fmaf(wv, F[dy + 1][dx],     acc[cg][1][0]);
                    acc[cg][1][1] = fmaf(wv, F[dy + 1][dx + 1], acc[cg][1][1]);
                }
            }
        }
    }

#pragma unroll
    for (int cg = 0; cg < COG; ++cg) {
        float v00 = acc[cg][0][0], v01 = acc[cg][0][1];
        float v10 = acc[cg][1][0], v11 = acc[cg][1][1];
        if (DOLEAKY) { v00 = leaky(v00); v01 = leaky(v01); v10 = leaky(v10); v11 = leaky(v11); }
        float* op = out + ((size_t)(k * CO + g * COG + cg)) * R * R + (2 * ty) * R + 2 * tx;
        float2 a; a.x = v00; a.y = v01; *(float2*)op = a;
        float2 b2; b2.x = v10; b2.y = v11; *(float2*)(op + R) = b2;
    }
}

// ================= dec2/dec3: 4-k same-parity block, LDS staged, 2x2 quads ===========
template<int R, int CP, int CF, int CO, int MINW, bool DOLEAKY>
__global__ void __launch_bounds__(256, MINW) deckq_k(
    const float* __restrict__ prev, const float* __restrict__ attn,
    const float* __restrict__ feat, const float* __restrict__ w,
    const float* __restrict__ bias, float* __restrict__ out)
{
    constexpr int CIN = CP + 1 + CF, Rh = R / 2, TX = R / 16;
    __shared__ float sf[CF * 324];          // [cf][18 rows][Fe 9 | Fo 9]
    __shared__ float sh[4][(CP + 1) * 100];
    __shared__ float ws[CO * CIN * 9 + CO];

    int t = threadIdx.x;
    int kg = blockIdx.y;
    int p = kg & 1;
    int kbase = (kg >> 1) * 8 + p;          // k = kbase + 2*j, j=0..3
    int tileY = blockIdx.x / TX, tileX = blockIdx.x % TX;
    int Y0 = 16 * tileY, X0 = 16 * tileX;
    int hy0 = 8 * tileY - 1, hx0 = 8 * tileX - 1;

    for (int i = t; i < CO * CIN * 9; i += 256) ws[i] = w[i];
    if (t < CO) ws[CO * CIN * 9 + t] = bias[t];

    for (int i = t; i < CF * 324; i += 256) {
        int c = i / 324, rem = i - c * 324;
        int r = rem / 18, wc = rem - r * 18;
        int gy = Y0 - 1 + r, gx = X0 - 1 + wc;
        float v = 0.f;
        if (gy >= 0 && gy < R && gx >= 0 && gx < R)
            v = feat[((size_t)(p * CF + c)) * R * R + gy * R + gx];
        sf[c * 324 + r * 18 + (wc & 1) * 9 + (wc >> 1)] = v;
    }
    for (int i = t; i < CP * 100; i += 256) {
        int c = i / 100, rem = i - c * 100;
        int r = rem / 10, col = rem - r * 10;
        int gy = hy0 + r, gx = hx0 + col;
        bool ok = (gy >= 0) && (gy < Rh) && (gx >= 0) && (gx < Rh);
        int off = gy * Rh + gx;
#pragma unroll
        for (int j = 0; j < 4; ++j) {
            float v = 0.f;
            if (ok) v = prev[((size_t)((kbase + 2 * j) * CP + c)) * Rh * Rh + off];
            sh[j][i] = v;
        }
    }
    if (t < 100) {
        int r = t / 10, col = t - r * 10;
        int gy = hy0 + r, gx = hx0 + col;
        bool ok = (gy >= 0) && (gy < Rh) && (gx >= 0) && (gx < Rh);
        int off = gy * Rh + gx;
#pragma unroll
        for (int j = 0; j < 4; ++j) {
            float v = 0.f;
            if (ok) v = attn[(size_t)(kbase + 2 * j) * Rh * Rh + off];
            sh[j][CP * 100 + t] = v;
        }
    }
    __syncthreads();

    int ksub = t >> 6, q = t & 63, qx = q & 7, qy = q >> 3;
    int k = kbase + 2 * ksub;

    float acc[CO][2][2];
#pragma unroll
    for (int co = 0; co < CO; ++co) {
        float b0 = ws[CO * CIN * 9 + co];
        acc[co][0][0] = b0; acc[co][0][1] = b0; acc[co][1][0] = b0; acc[co][1][1] = b0;
    }

#pragma unroll
    for (int ci = 0; ci < CP + 1; ++ci) {
        const float* hp = &sh[ksub][ci * 100 + qy * 10 + qx];
        float P[3][3];
#pragma unroll
        for (int i = 0; i < 3; ++i)
#pragma unroll
            for (int j = 0; j < 3; ++j) P[i][j] = hp[i * 10 + j];
#pragma unroll
        for (int co = 0; co < CO; ++co) {
#pragma unroll
            for (int dy = 0; dy < 3; ++dy) {
#pragma unroll
                for (int dx = 0; dx < 3; ++dx) {
                    float wv = ws[(co * CIN + ci) * 9 + dy * 3 + dx];
                    acc[co][0][0] = fmaf(wv, P[(0 + dy + 1) >> 1][(0 + dx + 1) >> 1], acc[co][0][0]);
                    acc[co][0][1] = fmaf(wv, P[(0 + dy + 1) >> 1][(1 + dx + 1) >> 1], acc[co][0][1]);
                    acc[co][1][0] = fmaf(wv, P[(1 + dy + 1) >> 1][(0 + dx + 1) >> 1], acc[co][1][0]);
                    acc[co][1][1] = fmaf(wv, P[(1 + dy + 1) >> 1][(1 + dx + 1) >> 1], acc[co][1][1]);
                }
            }
        }
    }
#pragma unroll
    for (int cf = 0; cf < CF; ++cf) {
        const float* fb = &sf[cf * 324];
        float F[4][4];
#pragma unroll
        for (int i = 0; i < 4; ++i) {
            int wr = (2 * qy + i) * 18;
            F[i][0] = fb[wr + qx];
            F[i][1] = fb[wr + 9 + qx];
            F[i][2] = fb[wr + qx + 1];
            F[i][3] = fb[wr + 9 + qx + 1];
        }
#pragma unroll
        for (int co = 0; co < CO; ++co) {
#pragma unroll
            for (int dy = 0; dy < 3; ++dy) {
#pragma unroll
                for (int dx = 0; dx < 3; ++dx) {
                    float wv = ws[(co * CIN + CP + 1 + cf) * 9 + dy * 3 + dx];
                    acc[co][0][0] = fmaf(wv, F[0 + dy][0 + dx], acc[co][0][0]);
                    acc[co][0][1] = fmaf(wv, F[0 + dy][1 + dx], acc[co][0][1]);
                    acc[co][1][0] = fmaf(wv, F[1 + dy][0 + dx], acc[co][1][0]);
                    acc[co][1][1] = fmaf(wv, F[1 + dy][1 + dx], acc[co][1][1]);
                }
            }
        }
    }

#pragma unroll
    for (int co = 0; co < CO; ++co) {
        float v00 = acc[co][0][0], v01 = acc[co][0][1];
        float v10 = acc[co][1][0], v11 = acc[co][1][1];
        if (DOLEAKY) { v00 = leaky(v00); v01 = leaky(v01); v10 = leaky(v10); v11 = leaky(v11); }
        float* op = out + ((size_t)(k * CO + co)) * R * R + (Y0 + 2 * qy) * R + X0 + 2 * qx;
        float2 a; a.x = v00; a.y = v01; *(float2*)op = a;
        float2 b2; b2.x = v10; b2.y = v11; *(float2*)(op + R) = b2;
    }
}

// ================= dec1: 4 same-parity k per block, 1 px x 4 k per thread ============
// Weights in LDS; each weight ds_read feeds 4 FMAs (one per k). Feat window shared
// across all 4 k; 1-px threads make feat reads lane-stride-1 (no bank conflicts).
__global__ void __launch_bounds__(256, 2) dec1c_k(
    const float* __restrict__ prev, const float* __restrict__ attn,
    const float* __restrict__ feat, const float* __restrict__ w,
    const float* __restrict__ bias, float* __restrict__ out)
{
    constexpr int R = 64, CP = 16, CF = 16, CIN = 33, Rh = 32, CO = 8;
    __shared__ float ws[CO * CIN * 9];          // 2376 f = 9.5 KB
    __shared__ float sf[CF * 324];              // [cf][18][18] = 20.7 KB
    __shared__ float sh[4][(CP + 1) * 100];     // [j][ci][10][10] = 27.2 KB

    int t = threadIdx.x;
    int kg = blockIdx.y;                 // 0..15
    int p = kg & 1;
    int kbase = (kg >> 1) * 8 + p;       // k = kbase + 2*j, j=0..3
    int tileY = blockIdx.x >> 2, tileX = blockIdx.x & 3;
    int Y0 = 16 * tileY, X0 = 16 * tileX;
    int hy0 = 8 * tileY - 1, hx0 = 8 * tileX - 1;

    for (int i = t; i < CO * CIN * 9; i += 256) ws[i] = w[i];
    // feat 18x18 window, origin (Y0-1, X0-1), plain layout
    for (int i = t; i < CF * 324; i += 256) {
        int c = i / 324, rem = i - c * 324;
        int r = rem / 18, col = rem - r * 18;
        int gy = Y0 - 1 + r, gx = X0 - 1 + col;
        float v = 0.f;
        if (gy >= 0 && gy < R && gx >= 0 && gx < R)
            v = feat[((size_t)(p * CF + c)) * R * R + gy * R + gx];
        sf[i] = v;
    }
    // half-res prev planes 10x10, shared addr math across the 4 k
    for (int i = t; i < CP * 100; i += 256) {
        int c = i / 100, rem = i - c * 100;
        int r = rem / 10, col = rem - r * 10;
        int gy = hy0 + r, gx = hx0 + col;
        bool ok = (gy >= 0) && (gy < Rh) && (gx >= 0) && (gx < Rh);
        int off = gy * Rh + gx;
#pragma unroll
        for (int j = 0; j < 4; ++j) {
            float v = 0.f;
            if (ok) v = prev[((size_t)((kbase + 2 * j) * CP + c)) * Rh * Rh + off];
            sh[j][i] = v;
        }
    }
    if (t < 100) {
        int r = t / 10, col = t - r * 10;
        int gy = hy0 + r, gx = hx0 + col;
        bool ok = (gy >= 0) && (gy < Rh) && (gx >= 0) && (gx < Rh);
        int off = gy * Rh + gx;
#pragma unroll
        for (int j = 0; j < 4; ++j) {
            float v = 0.f;
            if (ok) v = attn[(size_t)(kbase + 2 * j) * Rh * Rh + off];
            sh[j][CP * 100 + t] = v;
        }
    }
    __syncthreads();

    int qx = t & 15, qy = t >> 4;       // output pixel within 16x16 tile

    float acc[4][CO];
#pragma unroll
    for (int co = 0; co < CO; ++co) {
        float b0 = bias[co];
#pragma unroll
        for (int j = 0; j < 4; ++j) acc[j][co] = b0;
    }

    // half-patch indices: rel row/col for tap d = (q + d + 1) >> 1
    int rr[3] = {(qy + 1) >> 1, (qy + 2) >> 1, (qy + 3) >> 1};
    int cc[3] = {(qx + 1) >> 1, (qx + 2) >> 1, (qx + 3) >> 1};

    for (int ci = 0; ci < CP + 1; ++ci) {
        float P[4][3][3];
#pragma unroll
        for (int j = 0; j < 4; ++j) {
            const float* hp = &sh[j][ci * 100];
#pragma unroll
            for (int i = 0; i < 3; ++i)
#pragma unroll
                for (int j2 = 0; j2 < 3; ++j2)
                    P[j][i][j2] = hp[rr[i] * 10 + cc[j2]];
        }
        const float* wb = &ws[ci * 9];
#pragma unroll
        for (int co = 0; co < CO; ++co) {
#pragma unroll
            for (int dy = 0; dy < 3; ++dy) {
#pragma unroll
                for (int dx = 0; dx < 3; ++dx) {
                    float wv = wb[co * CIN * 9 + dy * 3 + dx];
#pragma unroll
                    for (int j = 0; j < 4; ++j)
                        acc[j][co] = fmaf(wv, P[j][dy][dx], acc[j][co]);
                }
            }
        }
    }

    for (int cf = 0; cf < CF; ++cf) {
        const float* fb = &sf[cf * 324 + qy * 18 + qx];
        float F[3][3];
#pragma unroll
        for (int i = 0; i < 3; ++i)
#pragma unroll
            for (int j2 = 0; j2 < 3; ++j2)
                F[i][j2] = fb[i * 18 + j2];
        const float* wb = &ws[(CP + 1 + cf) * 9];
#pragma unroll
        for (int co = 0; co < CO; ++co) {
#pragma unroll
            for (int dy = 0; dy < 3; ++dy) {
#pragma unroll
                for (int dx = 0; dx < 3; ++dx) {
                    float wv = wb[co * CIN * 9 + dy * 3 + dx];
#pragma unroll
                    for (int j = 0; j < 4; ++j)
                        acc[j][co] = fmaf(wv, F[dy][dx], acc[j][co]);
                }
            }
        }
    }

#pragma unroll
    for (int j = 0; j < 4; ++j) {
        int k = kbase + 2 * j;
#pragma unroll
        for (int co = 0; co < CO; ++co) {
            float v = leaky(acc[j][co]);
            out[((size_t)(k * CO + co)) * R * R + (Y0 + qy) * R + X0 + qx] = v;
        }
    }
}

extern "C" void kernel_launch(void* const* d_in, const int* in_sizes, int n_in,
                              void* d_out, int out_size, void* d_ws, size_t ws_size,
                              hipStream_t stream)
{
    (void)in_sizes; (void)n_in; (void)out_size; (void)ws_size;
    const float* x1 = (const float*)d_in[0];
    const float* x2 = (const float*)d_in[1];
    const int* pts = (const int*)d_in[2];
    const float* ew[4] = {(const float*)d_in[3], (const float*)d_in[5],
                          (const float*)d_in[7], (const float*)d_in[9]};
    const float* eb[4] = {(const float*)d_in[4], (const float*)d_in[6],
                          (const float*)d_in[8], (const float*)d_in[10]};
    const float* dw[4] = {(const float*)d_in[11], (const float*)d_in[13],
                          (const float*)d_in[15], (const float*)d_in[17]};
    const float* db[4] = {(const float*)d_in[12], (const float*)d_in[14],
                          (const float*)d_in[16], (const float*)d_in[18]};

    float* wsp = (float*)d_ws;
    size_t off = 0;
    auto A = [&](size_t n) { float* p = wsp + off; off += n; return p; };

    float* p0 = A((size_t)4 * 4 * 128 * 128);
    float* p1 = A((size_t)4 * 8 * 64 * 64);
    float* p2 = A((size_t)4 * 16 * 32 * 32);
    float* p3 = A((size_t)4 * 16 * 16 * 16);
    float* c2_0 = A((size_t)2 * 4 * 256 * 256);
    float* c2_1 = A((size_t)2 * 8 * 128 * 128);
    float* c2_2 = A((size_t)2 * 16 * 64 * 64);
    float* c2_3 = A((size_t)2 * 16 * 32 * 32);
    float* at0 = A((size_t)64 * 128 * 128);
    float* at1 = A((size_t)64 * 64 * 64);
    float* at2 = A((size_t)64 * 32 * 32);
    float* at3 = A((size_t)64 * 16 * 16);
    float* dec0 = A((size_t)64 * 16 * 32 * 32);
    float* dec1 = A((size_t)64 * 8 * 64 * 64);
    float* dec2 = A((size_t)64 * 4 * 128 * 128);
    float* outp = (float*)d_out;

    // ---- Encoder ----
    { dim3 g(64, 4); enc0_k<<<g, 256, 0, stream>>>(x1, x2, ew[0], eb[0], c2_0, p0); }
    enc_k<128, 4, 8, 2><<<512, 256, 0, stream>>>(p0, p0 + (size_t)2 * 4 * 128 * 128,
                                                 ew[1], eb[1], c2_1, p1);
    enc_k<64, 8, 16, 2><<<256, 256, 0, stream>>>(p1, p1 + (size_t)2 * 8 * 64 * 64,
                                                 ew[2], eb[2], c2_2, p2);
    enc_k<32, 16, 16, 1><<<128, 256, 0, stream>>>(p2, p2 + (size_t)2 * 16 * 32 * 32,
                                                  ew[3], eb[3], c2_3, p3);

    // ---- Attention: single launch for all 4 levels ----
    attn_all_k<<<170, 256, 0, stream>>>(p0, p1, p2, p3, pts, at0, at1, at2, at3);

    // ---- Decoder ----
    dec_k<32, 16, 16, 16, 4, true, true><<<256, 256, 0, stream>>>(p3, at3, c2_3, dw[0], db[0], dec0);
    // dec1: 4-k blocks, 16 tiles x 16 k-groups
    { dim3 g(16, 16); dec1c_k<<<g, 256, 0, stream>>>(dec0, at2, c2_2, dw[1], db[1], dec1); }
    { dim3 g(64, 16); deckq_k<128, 8, 8, 4, 4, true><<<g, 256, 0, stream>>>(dec1, at1, c2_1, dw[2], db[2], dec2); }
    { dim3 g(256, 16); deckq_k<256, 4, 4, 1, 5, false><<<g, 256, 0, stream>>>(dec2, at0, c2_0, dw[3], db[3], outp); }
}